// Round 4
// baseline (318.557 us; speedup 1.0000x reference)
//
#include <hip/hip_runtime.h>
#include <cstdint>
#include <cstddef>

// Problem constants
#define BB   2
#define SS   1024
#define HID  2048
#define HH   32
#define KVHH 8
#define DD   64
#define NQKV 3072   // fused QKV projection width: 2048 q + 512 k + 512 v
#define QKW  2560   // qk_bf row width: 2048 q + 512 k

typedef __attribute__((ext_vector_type(8))) short bf16x8;
typedef __attribute__((ext_vector_type(4))) float f32x4;

__device__ __forceinline__ unsigned short f2bf(float f) {
    unsigned int u = __float_as_uint(f);
    unsigned int r = (u + 0x7fffu + ((u >> 16) & 1u)) >> 16;
    return (unsigned short)r;
}

// ---------------------------------------------------------------------------
// prep: z=0..3 -> weight transpose+convert (Wq,Wk,Wv->WqkvT; Wo->WoT);
//       z=4    -> hidden fp32 -> bf16 straight convert.
// block (32,8), 32x32 tiles.
// ---------------------------------------------------------------------------
__global__ void prep(const float* __restrict__ hidden,
                     const float* __restrict__ Wq, const float* __restrict__ Wk,
                     const float* __restrict__ Wv, const float* __restrict__ Wo,
                     unsigned short* __restrict__ hidden_bf,
                     unsigned short* __restrict__ WqkvT,
                     unsigned short* __restrict__ WoT)
{
    const int z  = blockIdx.z;
    const int tx = threadIdx.x, ty = threadIdx.y;

    if (z == 4) {   // hidden convert, 2048x2048
        int r0 = blockIdx.y * 32, c0 = blockIdx.x * 32;
        #pragma unroll
        for (int i = 0; i < 4; ++i) {
            int row = r0 + ty * 4 + i;
            hidden_bf[(size_t)row * 2048 + c0 + tx] =
                f2bf(hidden[(size_t)row * 2048 + c0 + tx]);
        }
        return;
    }

    const float* W;
    unsigned short* Wt;
    int N;
    if (z == 0)      { W = Wq; Wt = WqkvT;                        N = 2048; }
    else if (z == 1) { W = Wk; Wt = WqkvT + (size_t)2048 * 2048;  N = 512;  }
    else if (z == 2) { W = Wv; Wt = WqkvT + (size_t)2560 * 2048;  N = 512;  }
    else             { W = Wo; Wt = WoT;                          N = 2048; }
    if (blockIdx.x * 32 >= N) return;

    __shared__ float t[32][33];
    const int n0 = blockIdx.x * 32, k0 = blockIdx.y * 32;
    #pragma unroll
    for (int i = 0; i < 4; ++i)
        t[ty * 4 + i][tx] = W[(size_t)(k0 + ty * 4 + i) * N + n0 + tx];
    __syncthreads();
    #pragma unroll
    for (int i = 0; i < 4; ++i)
        Wt[(size_t)(n0 + ty * 4 + i) * 2048 + k0 + tx] = f2bf(t[tx][ty * 4 + i]);
}

// ---------------------------------------------------------------------------
// bf16 MFMA GEMM, B-transposed: C(MxN fp32) = A(MxK bf16) @ Bt(NxK bf16)^T
// ---------------------------------------------------------------------------
__global__ __launch_bounds__(256) void gemm_bf16_bt(
    const unsigned short* __restrict__ A,
    const unsigned short* __restrict__ Bt,
    float* __restrict__ C, int M, int N, int K)
{
    __shared__ short As[128][32];
    __shared__ short Bs[128][32];

    const int tid  = threadIdx.x;
    const int lane = tid & 63;
    const int wave = tid >> 6;
    const int wm = (wave >> 1) * 64, wn = (wave & 1) * 64;
    const int m0 = blockIdx.y * 128, n0 = blockIdx.x * 128;

    f32x4 acc[4][4] = {};

    const int mrow = lane & 15;
    const int kq   = (lane >> 4) * 8;

    for (int k0 = 0; k0 < K; k0 += 32) {
        #pragma unroll
        for (int p = 0; p < 2; ++p) {
            int ci = tid + p * 256;
            int row = ci >> 2;
            int q = (ci & 3) * 8;
            *(int4*)&As[row][q] = *(const int4*)&A [(size_t)(m0 + row) * K + k0 + q];
            *(int4*)&Bs[row][q] = *(const int4*)&Bt[(size_t)(n0 + row) * K + k0 + q];
        }
        __syncthreads();

        bf16x8 af[4], bfr[4];
        #pragma unroll
        for (int i = 0; i < 4; ++i)
            af[i] = *(const bf16x8*)&As[wm + i * 16 + mrow][kq];
        #pragma unroll
        for (int j = 0; j < 4; ++j)
            bfr[j] = *(const bf16x8*)&Bs[wn + j * 16 + mrow][kq];

        #pragma unroll
        for (int i = 0; i < 4; ++i)
            #pragma unroll
            for (int j = 0; j < 4; ++j)
                acc[i][j] = __builtin_amdgcn_mfma_f32_16x16x32_bf16(
                    af[i], bfr[j], acc[i][j], 0, 0, 0);
        __syncthreads();
    }

    #pragma unroll
    for (int i = 0; i < 4; ++i) {
        int grow = m0 + wm + i * 16 + (lane >> 4) * 4;
        #pragma unroll
        for (int j = 0; j < 4; ++j) {
            int gcol = n0 + wn + j * 16 + (lane & 15);
            #pragma unroll
            for (int rg = 0; rg < 4; ++rg)
                C[(size_t)(grow + rg) * N + gcol] = acc[i][j][rg];
        }
    }
}

// ---------------------------------------------------------------------------
// postproc: flattened { rope q/k -> qk_bf bf16 } + { v transpose -> v_t bf16 }.
// blocks [0,10240): rope; [10240,11264): v transpose.
// ---------------------------------------------------------------------------
__global__ void postproc(const float* __restrict__ qkv,
                         unsigned short* __restrict__ qk_bf,
                         unsigned short* __restrict__ v_t)
{
    const int gb = blockIdx.x;
    if (gb < 10240) {
        const int r = gb >> 8;                              // 0..39
        const int t = threadIdx.x & 31;
        const int row = (gb & 255) * 8 + (threadIdx.x >> 5);
        const int s = row & (SS - 1);

        const float* src = qkv + (size_t)row * NQKV + r * 64;
        unsigned short* dst = qk_bf + (size_t)row * QKW + r * 64;

        float x1 = src[t];
        float x2 = src[t + 32];
        float inv = powf(10000.f, -(float)t * (1.f / 32.f));
        float ang = (float)s * inv;
        float c, sn;
        sincosf(ang, &sn, &c);
        float scale = (r < 32) ? 0.125f : 1.0f;
        dst[t]      = f2bf((x1 * c - x2 * sn) * scale);
        dst[t + 32] = f2bf((x2 * c + x1 * sn) * scale);
    } else {
        __shared__ float tls[32][33];
        const int id = gb - 10240;          // ((b*32 + sblk)*16 + cblk)
        const int cblk = id & 15;
        const int sblk = (id >> 4) & 31;
        const int b    = id >> 9;
        const int c0 = cblk * 32, s0 = sblk * 32;
        const int tx = threadIdx.x & 31, ty = threadIdx.x >> 5;
        #pragma unroll
        for (int i = 0; i < 4; ++i)
            tls[ty * 4 + i][tx] =
                qkv[(size_t)(b * SS + s0 + ty * 4 + i) * NQKV + 2560 + c0 + tx];
        __syncthreads();
        #pragma unroll
        for (int i = 0; i < 4; ++i)
            v_t[(size_t)(b * 512 + c0 + ty * 4 + i) * SS + s0 + tx] =
                f2bf(tls[tx][ty * 4 + i]);
    }
}

// ---------------------------------------------------------------------------
// Barrier-free GQA MFMA flash attention.
// Grid (16 qtiles, 8 kh, 2 b); block = 4 waves; wave w = head kh*4+w.
// Every MFMA fragment is loaded directly from global memory (contraction dim
// is contiguous for Q rows, K rows, and v_t rows). S^T = K.Q^T puts scores in
// C-layout with col=q=lane&15 == the A-frag m mapping needed for PV; only a
// wave-private LDS bounce (no barrier) re-spreads the k dim.
// Pass 1: l = sum exp(s+bias). Pass 2: w = relu(exp - c*l) -> PV; /l at end.
// NO __syncthreads in this kernel.
// ---------------------------------------------------------------------------
__global__ __launch_bounds__(256, 1) void attn_mfma(
    const unsigned short* __restrict__ qk_bf,   // [2048][2560]
    const unsigned short* __restrict__ v_t,     // [1024][1024]
    const float* __restrict__ bias_diag,
    const float* __restrict__ soff,
    unsigned short* __restrict__ AO)            // [2048][2048] bf16
{
    const int qt = blockIdx.x;
    const int kh = blockIdx.y;
    const int b  = blockIdx.z;
    const int wave = threadIdx.x >> 6;
    const int lane = threadIdx.x & 63;
    const int quad = lane >> 4;
    const int l15  = lane & 15;
    const int h  = kh * 4 + wave;
    const int q0 = qt * 64;

    __shared__ short Ws_all[4][64][72];
    __shared__ float bd_all[4][1024];
    short (*Ws)[72] = Ws_all[wave];
    float* bd = bd_all[wave];

    // wave-private bias row (no barrier needed)
    for (int i = lane; i < 1024; i += 64) bd[i] = bias_diag[h * 1024 + i];

    // Q fragments, direct from global (held for the whole kernel)
    bf16x8 Qf[4][2];
    const unsigned short* Qg = qk_bf + (size_t)(b * SS + q0) * QKW + h * 64;
    #pragma unroll
    for (int nq = 0; nq < 4; ++nq)
        #pragma unroll
        for (int s = 0; s < 2; ++s)
            Qf[nq][s] = *(const bf16x8*)&Qg[(size_t)(nq * 16 + l15) * QKW + s * 32 + quad * 8];

    const unsigned short* Kg = qk_bf + (size_t)(b * SS) * QKW + 2048 + kh * 64;
    const unsigned short* Vg = v_t + (size_t)(b * 512 + kh * 64) * SS;
    const int ntiles = qt + 1;

    // ---------------- pass 1: l ----------------
    float lp[4] = {0.f, 0.f, 0.f, 0.f};
    for (int j = 0; j < ntiles; ++j) {
        const int k0 = j * 64;
        bf16x8 Kf[4][2];
        #pragma unroll
        for (int nk = 0; nk < 4; ++nk)
            #pragma unroll
            for (int s = 0; s < 2; ++s)
                Kf[nk][s] = *(const bf16x8*)&Kg[(size_t)(k0 + nk * 16 + l15) * QKW + s * 32 + quad * 8];

        f32x4 st[4][4] = {};   // [nk][nq]: row kpos, col q
        #pragma unroll
        for (int s = 0; s < 2; ++s)
            #pragma unroll
            for (int nk = 0; nk < 4; ++nk)
                #pragma unroll
                for (int nq = 0; nq < 4; ++nq)
                    st[nk][nq] = __builtin_amdgcn_mfma_f32_16x16x32_bf16(
                        Kf[nk][s], Qf[nq][s], st[nk][nq], 0, 0, 0);

        if (j < qt) {          // fully-visible tile: rel >= 0 guaranteed
            #pragma unroll
            for (int nk = 0; nk < 4; ++nk)
                #pragma unroll
                for (int r = 0; r < 4; ++r) {
                    int kp = k0 + nk * 16 + quad * 4 + r;
                    #pragma unroll
                    for (int nq = 0; nq < 4; ++nq) {
                        int rel = (q0 + nq * 16 + l15) - kp;
                        lp[nq] += __expf(st[nk][nq][r] + bd[rel]);
                    }
                }
        } else {               // diagonal tile
            #pragma unroll
            for (int nk = 0; nk < 4; ++nk)
                #pragma unroll
                for (int r = 0; r < 4; ++r) {
                    int kp = k0 + nk * 16 + quad * 4 + r;
                    #pragma unroll
                    for (int nq = 0; nq < 4; ++nq) {
                        int rel = (q0 + nq * 16 + l15) - kp;
                        if (rel >= 0) lp[nq] += __expf(st[nk][nq][r] + bd[rel]);
                    }
                }
        }
    }
    // reduce over the 4 quads (same l15)
    #pragma unroll
    for (int nq = 0; nq < 4; ++nq) {
        lp[nq] += __shfl_xor(lp[nq], 16, 64);
        lp[nq] += __shfl_xor(lp[nq], 32, 64);
    }

    float offa = fabsf(soff[h] + 1.f);
    float invl[4], cl[4];
    #pragma unroll
    for (int nq = 0; nq < 4; ++nq) {
        invl[nq] = 1.f / lp[nq];
        cl[nq] = offa / (float)(q0 + nq * 16 + l15 + 1) * lp[nq];
    }

    // ---------------- pass 2: output ----------------
    f32x4 Oa[4][4] = {};       // [nq][nd]: row q, col d
    for (int j = 0; j < ntiles; ++j) {
        const int k0 = j * 64;
        bf16x8 Kf[4][2], Vf[4][2];
        #pragma unroll
        for (int nk = 0; nk < 4; ++nk)
            #pragma unroll
            for (int s = 0; s < 2; ++s)
                Kf[nk][s] = *(const bf16x8*)&Kg[(size_t)(k0 + nk * 16 + l15) * QKW + s * 32 + quad * 8];
        #pragma unroll
        for (int nd = 0; nd < 4; ++nd)
            #pragma unroll
            for (int c = 0; c < 2; ++c)
                Vf[nd][c] = *(const bf16x8*)&Vg[(size_t)(nd * 16 + l15) * SS + k0 + c * 32 + quad * 8];

        f32x4 st[4][4] = {};
        #pragma unroll
        for (int s = 0; s < 2; ++s)
            #pragma unroll
            for (int nk = 0; nk < 4; ++nk)
                #pragma unroll
                for (int nq = 0; nq < 4; ++nq)
                    st[nk][nq] = __builtin_amdgcn_mfma_f32_16x16x32_bf16(
                        Kf[nk][s], Qf[nq][s], st[nk][nq], 0, 0, 0);

        // w = relu(exp(s+bias) - c*l), stored transposed: Ws[q_local][kpos_local]
        if (j < qt) {
            #pragma unroll
            for (int nk = 0; nk < 4; ++nk)
                #pragma unroll
                for (int r = 0; r < 4; ++r) {
                    int kpl = nk * 16 + quad * 4 + r;
                    int kp  = k0 + kpl;
                    #pragma unroll
                    for (int nq = 0; nq < 4; ++nq) {
                        int rel = (q0 + nq * 16 + l15) - kp;
                        float w = fmaxf(__expf(st[nk][nq][r] + bd[rel]) - cl[nq], 0.f);
                        Ws[nq * 16 + l15][kpl] = (short)f2bf(w);
                    }
                }
        } else {
            #pragma unroll
            for (int nk = 0; nk < 4; ++nk)
                #pragma unroll
                for (int r = 0; r < 4; ++r) {
                    int kpl = nk * 16 + quad * 4 + r;
                    int kp  = k0 + kpl;
                    #pragma unroll
                    for (int nq = 0; nq < 4; ++nq) {
                        int rel = (q0 + nq * 16 + l15) - kp;
                        float w = 0.f;
                        if (rel >= 0)
                            w = fmaxf(__expf(st[nk][nq][r] + bd[rel]) - cl[nq], 0.f);
                        Ws[nq * 16 + l15][kpl] = (short)f2bf(w);
                    }
                }
        }

        // PV: A = W (m=q, from Ws), B = V^T (n=d), contraction over kpos
        #pragma unroll
        for (int c = 0; c < 2; ++c) {
            bf16x8 Wf[4];
            #pragma unroll
            for (int nq = 0; nq < 4; ++nq)
                Wf[nq] = *(const bf16x8*)&Ws[nq * 16 + l15][c * 32 + quad * 8];
            #pragma unroll
            for (int nq = 0; nq < 4; ++nq)
                #pragma unroll
                for (int nd = 0; nd < 4; ++nd)
                    Oa[nq][nd] = __builtin_amdgcn_mfma_f32_16x16x32_bf16(
                        Wf[nq], Vf[nd][c], Oa[nq][nd], 0, 0, 0);
        }
    }

    // epilogue: /l and store (invl lives at lane l15=q_local -> shuffle)
    #pragma unroll
    for (int nq = 0; nq < 4; ++nq)
        #pragma unroll
        for (int r = 0; r < 4; ++r) {
            float iv = __shfl(invl[nq], quad * 4 + r, 64);
            int q = q0 + nq * 16 + quad * 4 + r;
            #pragma unroll
            for (int nd = 0; nd < 4; ++nd)
                AO[(size_t)(b * SS + q) * 2048 + h * 64 + nd * 16 + l15] =
                    f2bf(Oa[nq][nd][r] * iv);
        }
}

// ---------------------------------------------------------------------------
extern "C" void kernel_launch(void* const* d_in, const int* in_sizes, int n_in,
                              void* d_out, int out_size, void* d_ws, size_t ws_size,
                              hipStream_t stream)
{
    const float* hidden    = (const float*)d_in[0];
    const float* Wq        = (const float*)d_in[2];
    const float* Wk        = (const float*)d_in[3];
    const float* Wv        = (const float*)d_in[4];
    const float* Wo        = (const float*)d_in[5];
    const float* bias_diag = (const float*)d_in[6];
    const float* soff      = (const float*)d_in[7];
    float* out = (float*)d_out;

    // Workspace aliasing (same 54.5 MB footprint as R3):
    //  region A [0, 20.97M):  hidden_bf(8.39M)+WqkvT(12.58M) --dead after QKV gemm-->
    //                         qk_bf(10.49M)+v_t(2.10M)
    //  region B [20.97M, 29.36M): WoT (8.39M)
    //  region C [29.36M, 54.53M): qkv fp32 (25.17M) --dead after postproc--> AO_bf(8.39M)
    char* wsb = (char*)d_ws;
    unsigned short* hidden_bf = (unsigned short*)wsb;
    unsigned short* WqkvT     = (unsigned short*)(wsb + (size_t)2048 * 2048 * 2);
    unsigned short* qk_bf     = (unsigned short*)wsb;
    unsigned short* v_t       = (unsigned short*)(wsb + (size_t)2048 * 2560 * 2);
    unsigned short* WoT       = (unsigned short*)(wsb + (size_t)20971520);
    float*          qkv       = (float*)(wsb + (size_t)29360128);
    unsigned short* AO_bf     = (unsigned short*)(wsb + (size_t)29360128);

    // 1. all weight transposes + hidden convert in one launch
    prep<<<dim3(64, 64, 5), dim3(32, 8), 0, stream>>>(
        hidden, Wq, Wk, Wv, Wo, hidden_bf, WqkvT, WoT);

    // 2. fused QKV projection (fp32 out)
    gemm_bf16_bt<<<dim3(NQKV / 128, 2048 / 128), dim3(256), 0, stream>>>(
        hidden_bf, WqkvT, qkv, 2048, NQKV, 2048);

    // 3. rope+convert q,k and v transpose in one launch
    postproc<<<dim3(11264), dim3(256), 0, stream>>>(qkv, qk_bf, v_t);

    // 4. barrier-free GQA MFMA attention -> AO_bf
    attn_mfma<<<dim3(16, KVHH, BB), dim3(256), 0, stream>>>(
        qk_bf, v_t, bias_diag, soff, AO_bf);

    // 5. output projection
    gemm_bf16_bt<<<dim3(2048 / 128, 2048 / 128), dim3(256), 0, stream>>>(
        AO_bf, WoT, out, 2048, 2048, 2048);
}